// Round 4
// baseline (992.170 us; speedup 1.0000x reference)
//
#include <hip/hip_runtime.h>
#include <math.h>

#define B_LEN 1024
#define T_LEN 256
#define HST 36   // hid_sh leading stride keeps float4 reads conflict-free

__device__ __forceinline__ float fast_rcp(float x) { return __builtin_amdgcn_rcpf(x); }
__device__ __forceinline__ float fast_rsq(float x) { return __builtin_amdgcn_rsqf(x); }
__device__ __forceinline__ float fast_tanh(float x) {
    float e = __expf(2.0f * x);
    return 1.0f - 2.0f * fast_rcp(e + 1.0f);
}
__device__ __forceinline__ float softplus_f(float x) {
    return (x > 20.0f) ? x : log1pf(expf(x));
}

// 2 batches per 256-thread block; each batch owns 2 waves (R3 structure).
// q = tid>>7 selects the batch slot; within a slot: wave0 = sequential state
// owner, wave1 = y-side + overlapped qe-slogdet. 512 blocks -> 4 waves/SIMD.
__global__ __launch_bounds__(256)
void ukf_kernel(const float* __restrict__ X0, const float* __restrict__ U,
                const float* __restrict__ Y,  const float* __restrict__ W1,
                const float* __restrict__ B1, const float* __restrict__ W2,
                const float* __restrict__ B2, const float* __restrict__ HM,
                const float* __restrict__ LQ, const float* __restrict__ LR,
                const float* __restrict__ LP0, float* __restrict__ out)
{
    const int tid  = threadIdx.x;
    const int q    = tid >> 7;        // batch slot in block
    const int t7   = tid & 127;       // thread within slot
    const int wid  = t7 >> 6;         // wave within slot
    const int lane = tid & 63;
    const int b    = blockIdx.x * 2 + q;
    const int i8   = lane >> 3;
    const int j8   = lane & 7;
    const int h32  = lane & 31;
    const int p4   = t7 >> 5;         // 0..3 (layer1 sigma group within slot)
    const int m4   = lane & 3;
    const int sy   = lane >> 2;
    const int s2   = t7 >> 3;         // 0..15 (layer2 sigma index)
    const int d2   = t7 & 7;          // == j8

    __shared__ float u_sh[2][T_LEN * 2];
    __shared__ float y_sh[2][T_LEN * 4];
    __shared__ __align__(16) float pts_sh[2][17 * 8];
    __shared__ __align__(16) float hid_sh[2][17 * HST];
    __shared__ __align__(16) float pf_sh[2][17 * 8];
    __shared__ __align__(16) float dx_sh[2][17 * 8];
    __shared__ __align__(16) float yp_sh[2][17 * 4];
    __shared__ float x_sh[2][8];
    __shared__ float xp_sh[2][8];
    __shared__ float ypred_sh[2][4];
    __shared__ float Sy_sh[2][16];
    __shared__ float L4_sh[2][16];
    __shared__ float Pxy_sh[2][32];
    __shared__ float K_sh[2][32];
    __shared__ float T1_sh[2][32];
    __shared__ float Pp_sh[2][64];

    // ---- one-time staging (each slot's 2 waves stage its batch) ----
    for (int k = t7; k < T_LEN * 2; k += 128) u_sh[q][k] = U[(size_t)b * (T_LEN * 2) + k];
    for (int k = t7; k < T_LEN * 4; k += 128) y_sh[q][k] = Y[(size_t)b * (T_LEN * 4) + k];

    float w1r[10];
    #pragma unroll
    for (int d = 0; d < 10; ++d) w1r[d] = W1[d * 32 + h32];
    const float b1r = B1[h32];
    float w2r[32];
    #pragma unroll
    for (int h = 0; h < 32; ++h) w2r[h] = W2[h * 8 + d2];
    const float b2r = B2[d2];
    float hmr[8];                              // used by wave1
    #pragma unroll
    for (int d = 0; d < 8; ++d) hmr[d] = HM[m4 * 8 + d];

    const float qdiag = softplus_f(LQ[i8]);
    const float rdiag = softplus_f(LR[m4]);

    const size_t Xbase = (size_t)b * T_LEN * 8;
    const size_t Pbase = (size_t)B_LEN * T_LEN * 8  + (size_t)b * T_LEN * 64;
    const size_t qbase = (size_t)B_LEN * T_LEN * 72 + (size_t)b * T_LEN;
    const size_t rbase = (size_t)B_LEN * T_LEN * 73 + (size_t)b * T_LEN;

    // ---- initial state / t=0 outputs ----
    float P = (i8 == j8) ? softplus_f(LP0[i8]) : 0.0f;   // wave0 owns P
    if (t7 < 8) x_sh[q][t7] = X0[b * 8 + t7];
    if (wid == 0) {
        if (lane < 8) out[Xbase + lane] = X0[b * 8 + lane];
        out[Pbase + lane] = P;
        if (lane == 0) { out[qbase] = 0.0f; out[rbase] = 0.0f; }
    }
    __syncthreads();

    for (int t = 1; t < T_LEN; ++t) {
        // ===== [w0] chol8(8P + jitter) in-register, sigma points -> LDS =======
        if (wid == 0) {
            float a = 8.0f * P + ((i8 == j8) ? 1e-4f : 0.0f);
            #pragma unroll
            for (int j = 0; j < 8; ++j) {
                float dj = __shfl(a, j * 9);
                float rv = fast_rsq(dj);
                if (j8 == j) a = (i8 == j) ? dj * rv : a * rv;
                float ci = __shfl(a, i8 * 8 + j);
                float cj = __shfl(a, j8 * 8 + j);
                if (i8 > j && j8 > j) a -= ci * cj;
            }
            const float Lx = (j8 <= i8) ? a : 0.0f;
            const float xi = x_sh[q][i8];
            if (j8 == 0) pts_sh[q][i8] = xi;
            pts_sh[q][(1 + j8) * 8 + i8] = xi + Lx;
            pts_sh[q][(9 + j8) * 8 + i8] = xi - Lx;
        }
        __syncthreads();   // b1: pts ready

        // ===== [both] layer 1: hidden = tanh([pts;u] W1 + b1) =================
        {
            const float u0 = u_sh[q][(t - 1) * 2 + 0];
            const float u1 = u_sh[q][(t - 1) * 2 + 1];
            const float ub = b1r + u0 * w1r[8] + u1 * w1r[9];
            #pragma unroll
            for (int k = 0; k < 5; ++k) {
                int s = 4 * k + p4;
                if (s < 17) {
                    const float4 pa = *(const float4*)&pts_sh[q][s * 8];
                    const float4 pb = *(const float4*)&pts_sh[q][s * 8 + 4];
                    float acc = ub
                        + pa.x * w1r[0] + pa.y * w1r[1] + pa.z * w1r[2] + pa.w * w1r[3]
                        + pb.x * w1r[4] + pb.y * w1r[5] + pb.z * w1r[6] + pb.w * w1r[7];
                    hid_sh[q][s * HST + h32] = fast_tanh(acc);
                }
            }
        }
        __syncthreads();   // b2: hid ready

        // ===== [both] layer 2: pf = pts + hid W2 + b2 =========================
        {
            float acc = b2r;
            #pragma unroll
            for (int h = 0; h < 32; h += 4) {
                const float4 hv = *(const float4*)&hid_sh[q][s2 * HST + h];
                acc += hv.x * w2r[h] + hv.y * w2r[h + 1] + hv.z * w2r[h + 2] + hv.w * w2r[h + 3];
            }
            pf_sh[q][s2 * 8 + d2] = pts_sh[q][s2 * 8 + d2] + acc;
            if (t7 < 8) {
                float a16 = b2r;
                #pragma unroll
                for (int h = 0; h < 32; h += 4) {
                    const float4 hv = *(const float4*)&hid_sh[q][16 * HST + h];
                    a16 += hv.x * w2r[h] + hv.y * w2r[h + 1] + hv.z * w2r[h + 2] + hv.w * w2r[h + 3];
                }
                pf_sh[q][16 * 8 + t7] = pts_sh[q][16 * 8 + t7] + a16;
            }
        }
        __syncthreads();   // b3: pf ready

        // ===== [w0] x_pred + dx ; [w1] y_pts + ypred + dy =====================
        if (wid == 0) {
            const float v0   = pf_sh[q][i8 * 8 + j8];
            const float v1   = pf_sh[q][(8 + i8) * 8 + j8];
            const float pf16 = (i8 == 0) ? pf_sh[q][16 * 8 + j8] : 0.0f;
            float part = ((i8 == 0) ? pf16 : v0) + v1;      // s=16 replaces s=0
            part += __shfl_xor(part, 8);
            part += __shfl_xor(part, 16);
            part += __shfl_xor(part, 32);
            const float xp = part * 0.0625f;
            if (i8 == 0) xp_sh[q][j8] = xp;
            dx_sh[q][i8 * 8 + j8]       = v0 - xp;
            dx_sh[q][(8 + i8) * 8 + j8] = v1 - xp;
            if (i8 == 0) dx_sh[q][16 * 8 + j8] = pf16 - xp;
        } else {
            float yv0, yv16 = 0.0f;
            {
                const float4 pa = *(const float4*)&pf_sh[q][sy * 8];
                const float4 pb = *(const float4*)&pf_sh[q][sy * 8 + 4];
                yv0 = pa.x * hmr[0] + pa.y * hmr[1] + pa.z * hmr[2] + pa.w * hmr[3]
                    + pb.x * hmr[4] + pb.y * hmr[5] + pb.z * hmr[6] + pb.w * hmr[7];
            }
            if (sy == 0) {
                const float4 pa = *(const float4*)&pf_sh[q][16 * 8];
                const float4 pb = *(const float4*)&pf_sh[q][16 * 8 + 4];
                yv16 = pa.x * hmr[0] + pa.y * hmr[1] + pa.z * hmr[2] + pa.w * hmr[3]
                     + pb.x * hmr[4] + pb.y * hmr[5] + pb.z * hmr[6] + pb.w * hmr[7];
            }
            float py = (sy == 0) ? yv16 : yv0;
            py += __shfl_xor(py, 4);
            py += __shfl_xor(py, 8);
            py += __shfl_xor(py, 16);
            py += __shfl_xor(py, 32);
            const float ypred = py * 0.0625f;
            if (lane < 4) ypred_sh[q][lane] = ypred;
            yp_sh[q][sy * 4 + m4] = yv0 - ypred;
            if (sy == 0) yp_sh[q][16 * 4 + m4] = yv16 - ypred;
        }
        __syncthreads();   // b4: dx, dy, xp, ypred ready

        // ===== [w0] P_pred -> reg + Pp_sh ; [w1] Sy + Pxy =====================
        float Ppred = 0.0f;
        if (wid == 0) {
            float pp = 0.0f;
            #pragma unroll
            for (int s = 1; s < 17; ++s)
                pp += dx_sh[q][s * 8 + i8] * dx_sh[q][s * 8 + j8];
            pp *= 0.0625f;
            pp += 2.0f * dx_sh[q][i8] * dx_sh[q][j8];         // Wc[0] = 2
            Ppred = pp + ((i8 == j8) ? (qdiag + 1e-4f) : 0.0f);
            Pp_sh[q][lane] = Ppred;
        } else {
            if (lane < 16) {
                float acc = 0.0f;
                #pragma unroll
                for (int s = 1; s < 17; ++s)
                    acc += yp_sh[q][s * 4 + sy] * yp_sh[q][s * 4 + m4];
                Sy_sh[q][lane] = acc * 0.0625f + 2.0f * yp_sh[q][sy] * yp_sh[q][m4]
                               + ((sy == m4) ? rdiag : 0.0f);
            } else if (lane < 48) {
                const int idx = lane - 16;
                const int ii = idx >> 2, mm = idx & 3;
                float acc = 0.0f;
                #pragma unroll
                for (int s = 1; s < 17; ++s)
                    acc += dx_sh[q][s * 8 + ii] * yp_sh[q][s * 4 + mm];
                Pxy_sh[q][idx] = acc * 0.0625f + 2.0f * dx_sh[q][ii] * yp_sh[q][mm];
            }
        }
        __syncthreads();   // b5: Ppred/Sy/Pxy ready

        if (wid == 0) {
            // ===== chol4(Sy) + r_e (lanes 0..15) ==============================
            float l4v = (lane < 16) ? Sy_sh[q][lane] : 0.0f;
            float re = 0.0f;
            #pragma unroll
            for (int j = 0; j < 4; ++j) {
                float dj = __shfl(l4v, j * 5);
                float rv = fast_rsq(dj);
                re += 0.5f * __logf(dj);
                if (lane < 16 && m4 == j) l4v = (sy == j) ? dj * rv : l4v * rv;
                float ci = __shfl(l4v, (sy * 4 + j) & 63);
                float cj = __shfl(l4v, (m4 * 4 + j) & 63);
                if (lane < 16 && sy > j && m4 > j) l4v -= ci * cj;
            }
            if (lane < 16) L4_sh[q][lane] = l4v;

            // ===== K = Pxy Sy^{-1} tri-solves (lanes 0..7) ====================
            if (lane < 8) {
                const float p0  = Pxy_sh[q][lane * 4 + 0];
                const float p1  = Pxy_sh[q][lane * 4 + 1];
                const float p2v = Pxy_sh[q][lane * 4 + 2];
                const float p3  = Pxy_sh[q][lane * 4 + 3];
                const float L00 = L4_sh[q][0],  L10 = L4_sh[q][4],  L11 = L4_sh[q][5];
                const float L20 = L4_sh[q][8],  L21 = L4_sh[q][9],  L22 = L4_sh[q][10];
                const float L30 = L4_sh[q][12], L31 = L4_sh[q][13], L32 = L4_sh[q][14], L33 = L4_sh[q][15];
                const float r0 = fast_rcp(L00), r1 = fast_rcp(L11);
                const float r2 = fast_rcp(L22), r3 = fast_rcp(L33);
                const float w0_ = p0 * r0;
                const float w1_ = (p1 - L10 * w0_) * r1;
                const float w2_ = (p2v - L20 * w0_ - L21 * w1_) * r2;
                const float w3_ = (p3 - L30 * w0_ - L31 * w1_ - L32 * w2_) * r3;
                const float k3 = w3_ * r3;
                const float k2 = (w2_ - L32 * k3) * r2;
                const float k1 = (w1_ - L21 * k2 - L31 * k3) * r1;
                const float k0 = (w0_ - L10 * k1 - L20 * k2 - L30 * k3) * r0;
                K_sh[q][lane * 4 + 0] = k0;
                K_sh[q][lane * 4 + 1] = k1;
                K_sh[q][lane * 4 + 2] = k2;
                K_sh[q][lane * 4 + 3] = k3;
            }
            // ===== T1 = K * Sy (lanes 0..31), intra-wave through LDS ==========
            if (lane < 32) {
                const int ii = lane >> 2, aa = lane & 3;
                T1_sh[q][lane] = K_sh[q][ii * 4 + 0] * Sy_sh[q][0 + aa]
                               + K_sh[q][ii * 4 + 1] * Sy_sh[q][4 + aa]
                               + K_sh[q][ii * 4 + 2] * Sy_sh[q][8 + aa]
                               + K_sh[q][ii * 4 + 3] * Sy_sh[q][12 + aa];
            }
            // ===== P_new = sym(Ppred - T1 K^T) + 1e-4 I =======================
            float m_ = Ppred - (T1_sh[q][i8 * 4 + 0] * K_sh[q][j8 * 4 + 0]
                              + T1_sh[q][i8 * 4 + 1] * K_sh[q][j8 * 4 + 1]
                              + T1_sh[q][i8 * 4 + 2] * K_sh[q][j8 * 4 + 2]
                              + T1_sh[q][i8 * 4 + 3] * K_sh[q][j8 * 4 + 3]);
            float mT = __shfl(m_, j8 * 8 + i8);
            P = 0.5f * (m_ + mT) + ((i8 == j8) ? 1e-4f : 0.0f);
            out[Pbase + (size_t)t * 64 + lane] = P;

            // ===== x_new (lanes 0..7) =========================================
            if (lane < 8) {
                const float in0 = y_sh[q][t * 4 + 0] - ypred_sh[q][0];
                const float in1 = y_sh[q][t * 4 + 1] - ypred_sh[q][1];
                const float in2 = y_sh[q][t * 4 + 2] - ypred_sh[q][2];
                const float in3 = y_sh[q][t * 4 + 3] - ypred_sh[q][3];
                const float xn = xp_sh[q][lane]
                    + K_sh[q][lane * 4 + 0] * in0 + K_sh[q][lane * 4 + 1] * in1
                    + K_sh[q][lane * 4 + 2] * in2 + K_sh[q][lane * 4 + 3] * in3;
                x_sh[q][lane] = xn;
                out[Xbase + (size_t)t * 8 + lane] = xn;
            }
            if (lane == 0) out[rbase + t] = re;
        } else {
            // ===== [w1] q_e = 0.5 slogdet(P_pred) via chol8 (overlapped) ======
            float ap = Pp_sh[q][lane];
            float qe = 0.0f;
            #pragma unroll
            for (int j = 0; j < 8; ++j) {
                float dj = __shfl(ap, j * 9);
                float rv = fast_rsq(dj);
                qe += 0.5f * __logf(dj);
                if (j8 == j) ap = (i8 == j) ? dj * rv : ap * rv;
                float ci = __shfl(ap, i8 * 8 + j);
                float cj = __shfl(ap, j8 * 8 + j);
                if (i8 > j && j8 > j) ap -= ci * cj;
            }
            if (lane == 0) out[qbase + t] = qe;
        }
        // next iteration's b1 doubles as the end-of-step barrier
    }
}

extern "C" void kernel_launch(void* const* d_in, const int* in_sizes, int n_in,
                              void* d_out, int out_size, void* d_ws, size_t ws_size,
                              hipStream_t stream) {
    (void)in_sizes; (void)n_in; (void)out_size; (void)d_ws; (void)ws_size;
    const float* X0 = (const float*)d_in[0];
    const float* U  = (const float*)d_in[1];
    const float* Y  = (const float*)d_in[2];
    const float* W1 = (const float*)d_in[3];
    const float* B1 = (const float*)d_in[4];
    const float* W2 = (const float*)d_in[5];
    const float* B2 = (const float*)d_in[6];
    const float* HM = (const float*)d_in[7];
    const float* LQ = (const float*)d_in[8];
    const float* LR = (const float*)d_in[9];
    const float* LP0 = (const float*)d_in[10];
    float* out = (float*)d_out;
    ukf_kernel<<<dim3(B_LEN / 2), dim3(256), 0, stream>>>(X0, U, Y, W1, B1, W2, B2,
                                                          HM, LQ, LR, LP0, out);
}

// Round 5
// 965.584 us; speedup vs baseline: 1.0275x; 1.0275x over previous
//
#include <hip/hip_runtime.h>
#include <math.h>

#define B_LEN 1024
#define T_LEN 256
#define HST 36   // hid_sh leading stride keeps float4 access conflict-light

__device__ __forceinline__ float fast_rcp(float x) { return __builtin_amdgcn_rcpf(x); }
__device__ __forceinline__ float fast_rsq(float x) { return __builtin_amdgcn_rsqf(x); }
__device__ __forceinline__ float lane_bcast(float v, int l) {
    return __int_as_float(__builtin_amdgcn_readlane(__float_as_int(v), l));
}
__device__ __forceinline__ float fast_tanh(float x) {
    float e = __expf(2.0f * x);
    return 1.0f - 2.0f * fast_rcp(e + 1.0f);
}
__device__ __forceinline__ float softplus_f(float x) {
    return (x > 20.0f) ? x : log1pf(expf(x));
}

// One batch per 128-thread block (2 waves). 2048 waves -> 2 waves/SIMD.
// wave0 keeps x and P *in registers across steps*: P column-per-lane
// (lane k8=lane&7 holds column k8, replicated over g8=lane>>3 groups).
// Factorizations are register-serial with v_readlane broadcasts (no
// ds_bpermute chains). wave1: y-side, Sy/Pxy, and qe-LDL overlapped with
// wave0's measurement update. 4 barriers/step.
__global__ __launch_bounds__(128, 2)
void ukf_kernel(const float* __restrict__ X0, const float* __restrict__ U,
                const float* __restrict__ Y,  const float* __restrict__ W1,
                const float* __restrict__ B1, const float* __restrict__ W2,
                const float* __restrict__ B2, const float* __restrict__ HM,
                const float* __restrict__ LQ, const float* __restrict__ LR,
                const float* __restrict__ LP0, float* __restrict__ out)
{
    const int tid  = threadIdx.x;
    const int wid  = tid >> 6;
    const int lane = tid & 63;
    const int b    = blockIdx.x;
    const int k8   = lane & 7;        // column / j8 / d2
    const int g8   = lane >> 3;       // replica group / i8 / s2
    const int i8   = g8;
    const int j8   = k8;
    const int h32  = lane & 31;
    const int p2   = lane >> 5;       // 0..1 (L1 sigma parity within wave)
    const int m4   = lane & 3;
    const int sy   = lane >> 2;

    __shared__ __align__(16) float u_sh[T_LEN * 2];
    __shared__ __align__(16) float y_sh[T_LEN * 4];
    __shared__ __align__(16) float pts_sh[17 * 8];
    __shared__ __align__(16) float hid_sh[17 * HST];
    __shared__ __align__(16) float pf_sh[17 * 8];
    __shared__ __align__(16) float dx_sh[17 * 8];
    __shared__ __align__(16) float yp_sh[17 * 4];
    __shared__ __align__(16) float xp_sh[8];
    __shared__ __align__(16) float ypred_sh[4];
    __shared__ __align__(16) float Sy_sh[16];
    __shared__ __align__(16) float Pxy_sh[32];
    __shared__ __align__(16) float K_sh[32];
    __shared__ __align__(16) float Pp_sh[64];

    // ---- one-time staging ----
    for (int k = tid; k < T_LEN * 2; k += 128) u_sh[k] = U[(size_t)b * (T_LEN * 2) + k];
    for (int k = tid; k < T_LEN * 4; k += 128) y_sh[k] = Y[(size_t)b * (T_LEN * 4) + k];

    float w1r[10];
    #pragma unroll
    for (int d = 0; d < 10; ++d) w1r[d] = W1[d * 32 + h32];
    const float b1r = B1[h32];
    float w2r[32];
    #pragma unroll
    for (int h = 0; h < 32; ++h) w2r[h] = W2[h * 8 + k8];
    const float b2r = B2[k8];
    float hmr[8];                              // wave1 only
    #pragma unroll
    for (int d = 0; d < 8; ++d) hmr[d] = HM[m4 * 8 + d];

    const float qdiag = softplus_f(LQ[i8]);    // wave0 (i8,j8) layout
    const float rdiag = softplus_f(LR[m4]);    // wave1 Sy

    const size_t Xbase = (size_t)b * T_LEN * 8;
    const size_t Pbase = (size_t)B_LEN * T_LEN * 8  + (size_t)b * T_LEN * 64;
    const size_t qbase = (size_t)B_LEN * T_LEN * 72 + (size_t)b * T_LEN;
    const size_t rbase = (size_t)B_LEN * T_LEN * 73 + (size_t)b * T_LEN;

    // ---- persistent register state (wave0): x replicated, P column k8 ----
    float xn[8], Pc[8];
    {
        const float4 xa = *(const float4*)&X0[b * 8];
        const float4 xb = *(const float4*)&X0[b * 8 + 4];
        xn[0] = xa.x; xn[1] = xa.y; xn[2] = xa.z; xn[3] = xa.w;
        xn[4] = xb.x; xn[5] = xb.y; xn[6] = xb.z; xn[7] = xb.w;
        const float p0k = softplus_f(LP0[k8]);
        #pragma unroll
        for (int i = 0; i < 8; ++i) Pc[i] = (i == k8) ? p0k : 0.0f;
    }
    if (wid == 0) {
        if (g8 == 0) {
            #pragma unroll
            for (int i = 0; i < 8; ++i) out[Pbase + i * 8 + k8] = Pc[i];
        }
        if (lane == 0) {
            *(float4*)&out[Xbase]     = make_float4(xn[0], xn[1], xn[2], xn[3]);
            *(float4*)&out[Xbase + 4] = make_float4(xn[4], xn[5], xn[6], xn[7]);
            out[qbase] = 0.0f; out[rbase] = 0.0f;
        }
    }

    for (int t = 1; t < T_LEN; ++t) {
        // ===== Phase A [w0]: column-chol8 of 8P+jitter, sigma pts -> LDS ======
        if (wid == 0) {
            float a[8];
            #pragma unroll
            for (int i = 0; i < 8; ++i) a[i] = 8.0f * Pc[i] + ((i == k8) ? 1e-4f : 0.0f);
            #pragma unroll
            for (int j = 0; j < 8; ++j) {
                const float dj  = lane_bcast(a[j], j);
                const float rv  = fast_rsq(dj);
                const float rv2 = rv * rv;
                float u[8];
                #pragma unroll
                for (int i = j + 1; i < 8; ++i) u[i] = lane_bcast(a[i], j);
                if (k8 == j) {
                    a[j] = dj * rv;
                    #pragma unroll
                    for (int i = j + 1; i < 8; ++i) a[i] *= rv;
                } else if (k8 > j) {
                    const float tt = a[j] * rv2;
                    #pragma unroll
                    for (int i = j + 1; i < 8; ++i) a[i] = fmaf(-tt, u[i], a[i]);
                }
            }
            float Lc[8];
            #pragma unroll
            for (int i = 0; i < 8; ++i) Lc[i] = (i >= k8) ? a[i] : 0.0f;
            if (g8 == 0) {
                *(float4*)&pts_sh[(1 + k8) * 8] =
                    make_float4(xn[0] + Lc[0], xn[1] + Lc[1], xn[2] + Lc[2], xn[3] + Lc[3]);
                *(float4*)&pts_sh[(1 + k8) * 8 + 4] =
                    make_float4(xn[4] + Lc[4], xn[5] + Lc[5], xn[6] + Lc[6], xn[7] + Lc[7]);
            } else if (g8 == 1) {
                *(float4*)&pts_sh[(9 + k8) * 8] =
                    make_float4(xn[0] - Lc[0], xn[1] - Lc[1], xn[2] - Lc[2], xn[3] - Lc[3]);
                *(float4*)&pts_sh[(9 + k8) * 8 + 4] =
                    make_float4(xn[4] - Lc[4], xn[5] - Lc[5], xn[6] - Lc[6], xn[7] - Lc[7]);
            } else if (g8 == 2 && k8 == 0) {
                *(float4*)&pts_sh[0] = make_float4(xn[0], xn[1], xn[2], xn[3]);
                *(float4*)&pts_sh[4] = make_float4(xn[4], xn[5], xn[6], xn[7]);
            }
        }
        __syncthreads();   // b1: pts ready

        // ===== Phase B [both]: fused L1+L2, per-wave sigma sets ===============
        {
            const float u0 = u_sh[(t - 1) * 2 + 0];
            const float u1 = u_sh[(t - 1) * 2 + 1];
            const float ub = b1r + u0 * w1r[8] + u1 * w1r[9];
            if (wid == 0) {
                #pragma unroll
                for (int p = 0; p < 4; ++p) {
                    const int s = 2 * p + p2;                 // 0..7
                    const float4 pa = *(const float4*)&pts_sh[s * 8];
                    const float4 pb = *(const float4*)&pts_sh[s * 8 + 4];
                    float acc = ub
                        + pa.x * w1r[0] + pa.y * w1r[1] + pa.z * w1r[2] + pa.w * w1r[3]
                        + pb.x * w1r[4] + pb.y * w1r[5] + pb.z * w1r[6] + pb.w * w1r[7];
                    hid_sh[s * HST + h32] = fast_tanh(acc);
                }
            } else {
                #pragma unroll
                for (int p = 0; p < 4; ++p) {
                    const int s = 8 + 2 * p + p2;             // 8..15
                    const float4 pa = *(const float4*)&pts_sh[s * 8];
                    const float4 pb = *(const float4*)&pts_sh[s * 8 + 4];
                    float acc = ub
                        + pa.x * w1r[0] + pa.y * w1r[1] + pa.z * w1r[2] + pa.w * w1r[3]
                        + pb.x * w1r[4] + pb.y * w1r[5] + pb.z * w1r[6] + pb.w * w1r[7];
                    hid_sh[s * HST + h32] = fast_tanh(acc);
                }
                if (p2 == 0) {                                // s = 16
                    const float4 pa = *(const float4*)&pts_sh[16 * 8];
                    const float4 pb = *(const float4*)&pts_sh[16 * 8 + 4];
                    float acc = ub
                        + pa.x * w1r[0] + pa.y * w1r[1] + pa.z * w1r[2] + pa.w * w1r[3]
                        + pb.x * w1r[4] + pb.y * w1r[5] + pb.z * w1r[6] + pb.w * w1r[7];
                    hid_sh[16 * HST + h32] = fast_tanh(acc);
                }
            }
            // L2 on own-wave rows (same-wave DS ops are in-order: no barrier)
            const int srow = (wid == 0) ? g8 : (8 + g8);
            float acc = b2r;
            #pragma unroll
            for (int h = 0; h < 32; h += 4) {
                const float4 hv = *(const float4*)&hid_sh[srow * HST + h];
                acc += hv.x * w2r[h] + hv.y * w2r[h + 1] + hv.z * w2r[h + 2] + hv.w * w2r[h + 3];
            }
            pf_sh[srow * 8 + k8] = pts_sh[srow * 8 + k8] + acc;
            if (wid == 1 && lane < 8) {
                float a16 = b2r;
                #pragma unroll
                for (int h = 0; h < 32; h += 4) {
                    const float4 hv = *(const float4*)&hid_sh[16 * HST + h];
                    a16 += hv.x * w2r[h] + hv.y * w2r[h + 1] + hv.z * w2r[h + 2] + hv.w * w2r[h + 3];
                }
                pf_sh[16 * 8 + lane] = pts_sh[16 * 8 + lane] + a16;
            }
        }
        __syncthreads();   // b2: pf ready

        // ===== Phase C [w0]: x_pred + dx ; [w1]: y_pts + ypred + dy ===========
        if (wid == 0) {
            const float v0   = pf_sh[i8 * 8 + j8];
            const float v1   = pf_sh[(8 + i8) * 8 + j8];
            const float pf16 = (i8 == 0) ? pf_sh[16 * 8 + j8] : 0.0f;
            float part = ((i8 == 0) ? pf16 : v0) + v1;        // s=16 replaces s=0
            part += __shfl_xor(part, 8);
            part += __shfl_xor(part, 16);
            part += __shfl_xor(part, 32);
            const float xp = part * 0.0625f;
            if (i8 == 0) xp_sh[j8] = xp;
            dx_sh[i8 * 8 + j8]       = v0 - xp;
            dx_sh[(8 + i8) * 8 + j8] = v1 - xp;
            if (i8 == 0) dx_sh[16 * 8 + j8] = pf16 - xp;
        } else {
            float yv0, yv16 = 0.0f;
            {
                const float4 pa = *(const float4*)&pf_sh[sy * 8];
                const float4 pb = *(const float4*)&pf_sh[sy * 8 + 4];
                yv0 = pa.x * hmr[0] + pa.y * hmr[1] + pa.z * hmr[2] + pa.w * hmr[3]
                    + pb.x * hmr[4] + pb.y * hmr[5] + pb.z * hmr[6] + pb.w * hmr[7];
            }
            if (sy == 0) {
                const float4 pa = *(const float4*)&pf_sh[16 * 8];
                const float4 pb = *(const float4*)&pf_sh[16 * 8 + 4];
                yv16 = pa.x * hmr[0] + pa.y * hmr[1] + pa.z * hmr[2] + pa.w * hmr[3]
                     + pb.x * hmr[4] + pb.y * hmr[5] + pb.z * hmr[6] + pb.w * hmr[7];
            }
            float py = (sy == 0) ? yv16 : yv0;
            py += __shfl_xor(py, 4);
            py += __shfl_xor(py, 8);
            py += __shfl_xor(py, 16);
            py += __shfl_xor(py, 32);
            const float ypred = py * 0.0625f;
            if (lane < 4) ypred_sh[lane] = ypred;
            yp_sh[sy * 4 + m4] = yv0 - ypred;
            if (sy == 0) yp_sh[16 * 4 + m4] = yv16 - ypred;
        }
        __syncthreads();   // b3: dx, dy, xp, ypred ready

        // ===== Phase D [w0]: Ppred -> Pp_sh + column regs ; [w1]: Sy + Pxy ====
        float Ppc[8];
        if (wid == 0) {
            float pp = 0.0f;
            #pragma unroll
            for (int s = 1; s < 17; ++s)
                pp += dx_sh[s * 8 + i8] * dx_sh[s * 8 + j8];
            pp *= 0.0625f;
            pp += 2.0f * dx_sh[i8] * dx_sh[j8];               // Wc[0] = 2
            const float Ppred = pp + ((i8 == j8) ? (qdiag + 1e-4f) : 0.0f);
            Pp_sh[lane] = Ppred;
            #pragma unroll
            for (int i = 0; i < 8; ++i) Ppc[i] = Pp_sh[i * 8 + k8];   // in-order
        } else {
            if (lane < 16) {
                float acc = 0.0f;
                #pragma unroll
                for (int s = 1; s < 17; ++s)
                    acc += yp_sh[s * 4 + sy] * yp_sh[s * 4 + m4];
                Sy_sh[lane] = acc * 0.0625f + 2.0f * yp_sh[sy] * yp_sh[m4]
                            + ((sy == m4) ? rdiag : 0.0f);
            } else if (lane < 48) {
                const int idx = lane - 16;
                const int ii = idx >> 2, mm = idx & 3;
                float acc = 0.0f;
                #pragma unroll
                for (int s = 1; s < 17; ++s)
                    acc += dx_sh[s * 8 + ii] * yp_sh[s * 4 + mm];
                Pxy_sh[idx] = acc * 0.0625f + 2.0f * dx_sh[ii] * yp_sh[mm];
            }
        }
        __syncthreads();   // b4: Pp_sh / Sy / Pxy ready

        // ===== Phase E ========================================================
        if (wid == 0) {
            // replicated serial chol4 of Sy + r_e
            float s_[16];
            {
                const float4 r0v = *(const float4*)&Sy_sh[0];
                const float4 r1v = *(const float4*)&Sy_sh[4];
                const float4 r2v = *(const float4*)&Sy_sh[8];
                const float4 r3v = *(const float4*)&Sy_sh[12];
                s_[0]=r0v.x;  s_[1]=r0v.y;  s_[2]=r0v.z;  s_[3]=r0v.w;
                s_[4]=r1v.x;  s_[5]=r1v.y;  s_[6]=r1v.z;  s_[7]=r1v.w;
                s_[8]=r2v.x;  s_[9]=r2v.y;  s_[10]=r2v.z; s_[11]=r2v.w;
                s_[12]=r3v.x; s_[13]=r3v.y; s_[14]=r3v.z; s_[15]=r3v.w;
            }
            const float d0 = s_[0];
            const float r0 = fast_rsq(d0);
            const float L10 = s_[4] * r0, L20 = s_[8] * r0, L30 = s_[12] * r0;
            const float d1 = s_[5] - L10 * L10;
            const float r1 = fast_rsq(d1);
            const float L21 = (s_[9]  - L20 * L10) * r1;
            const float L31 = (s_[13] - L30 * L10) * r1;
            const float d2_ = s_[10] - L20 * L20 - L21 * L21;
            const float r2 = fast_rsq(d2_);
            const float L32 = (s_[14] - L30 * L20 - L31 * L21) * r2;
            const float d3 = s_[15] - L30 * L30 - L31 * L31 - L32 * L32;
            const float r3 = fast_rsq(d3);
            const float re = 0.5f * (__logf(d0) + __logf(d1) + __logf(d2_) + __logf(d3));

            // K row k8 (replicated over g8); 1/L_ii == r_i
            const float4 pr = *(const float4*)&Pxy_sh[k8 * 4];
            const float w0_ = pr.x * r0;
            const float w1_ = (pr.y - L10 * w0_) * r1;
            const float w2_ = (pr.z - L20 * w0_ - L21 * w1_) * r2;
            const float w3_ = (pr.w - L30 * w0_ - L31 * w1_ - L32 * w2_) * r3;
            const float kk3 = w3_ * r3;
            const float kk2 = (w2_ - L32 * kk3) * r2;
            const float kk1 = (w1_ - L21 * kk2 - L31 * kk3) * r1;
            const float kk0 = (w0_ - L10 * kk1 - L20 * kk2 - L30 * kk3) * r0;
            if (g8 == 0) *(float4*)&K_sh[k8 * 4] = make_float4(kk0, kk1, kk2, kk3);

            // full K back (uniform broadcast reads; same-wave in-order)
            float K_[32];
            #pragma unroll
            for (int r = 0; r < 8; ++r) {
                const float4 kr = *(const float4*)&K_sh[r * 4];
                K_[r * 4 + 0] = kr.x; K_[r * 4 + 1] = kr.y;
                K_[r * 4 + 2] = kr.z; K_[r * 4 + 3] = kr.w;
            }
            // w4 = Sy * K[k8]^T ; P_new column k8 = Ppc - K*w4 (+jitter)
            float w4[4];
            #pragma unroll
            for (int aa = 0; aa < 4; ++aa)
                w4[aa] = s_[aa * 4 + 0] * kk0 + s_[aa * 4 + 1] * kk1
                       + s_[aa * 4 + 2] * kk2 + s_[aa * 4 + 3] * kk3;
            #pragma unroll
            for (int i = 0; i < 8; ++i) {
                const float m = K_[i * 4 + 0] * w4[0] + K_[i * 4 + 1] * w4[1]
                              + K_[i * 4 + 2] * w4[2] + K_[i * 4 + 3] * w4[3];
                Pc[i] = Ppc[i] - m + ((i == k8) ? 1e-4f : 0.0f);
            }
            // x_new (replicated)
            const float4 yt = *(const float4*)&y_sh[t * 4];
            const float4 yp = *(const float4*)&ypred_sh[0];
            const float in0 = yt.x - yp.x, in1 = yt.y - yp.y;
            const float in2 = yt.z - yp.z, in3 = yt.w - yp.w;
            const float4 xpa = *(const float4*)&xp_sh[0];
            const float4 xpb = *(const float4*)&xp_sh[4];
            float xpv[8] = {xpa.x, xpa.y, xpa.z, xpa.w, xpb.x, xpb.y, xpb.z, xpb.w};
            #pragma unroll
            for (int i = 0; i < 8; ++i)
                xn[i] = xpv[i] + K_[i * 4 + 0] * in0 + K_[i * 4 + 1] * in1
                               + K_[i * 4 + 2] * in2 + K_[i * 4 + 3] * in3;
            // stores
            if (g8 == 0) {
                #pragma unroll
                for (int i = 0; i < 8; ++i)
                    out[Pbase + (size_t)t * 64 + i * 8 + k8] = Pc[i];
            }
            if (lane == 0) {
                *(float4*)&out[Xbase + (size_t)t * 8]     = make_float4(xn[0], xn[1], xn[2], xn[3]);
                *(float4*)&out[Xbase + (size_t)t * 8 + 4] = make_float4(xn[4], xn[5], xn[6], xn[7]);
                out[rbase + t] = re;
            }
        } else {
            // [w1] qe = 0.5 slogdet(P_pred): column LDL, diag-only
            float aq[8];
            #pragma unroll
            for (int i = 0; i < 8; ++i) aq[i] = Pp_sh[i * 8 + k8];
            float qe = 0.0f;
            #pragma unroll
            for (int j = 0; j < 8; ++j) {
                const float dj  = lane_bcast(aq[j], j);
                qe += 0.5f * __logf(dj);
                const float rv2 = fast_rcp(dj);
                float u[8];
                #pragma unroll
                for (int i = j + 1; i < 8; ++i) u[i] = lane_bcast(aq[i], j);
                if (k8 > j) {
                    const float tt = aq[j] * rv2;
                    #pragma unroll
                    for (int i = j + 1; i < 8; ++i) aq[i] = fmaf(-tt, u[i], aq[i]);
                }
            }
            if (lane == 0) out[qbase + t] = qe;
        }
        // no trailing barrier: next-step hazards are covered by b1..b4 ordering
    }
}

extern "C" void kernel_launch(void* const* d_in, const int* in_sizes, int n_in,
                              void* d_out, int out_size, void* d_ws, size_t ws_size,
                              hipStream_t stream) {
    (void)in_sizes; (void)n_in; (void)out_size; (void)d_ws; (void)ws_size;
    const float* X0 = (const float*)d_in[0];
    const float* U  = (const float*)d_in[1];
    const float* Y  = (const float*)d_in[2];
    const float* W1 = (const float*)d_in[3];
    const float* B1 = (const float*)d_in[4];
    const float* W2 = (const float*)d_in[5];
    const float* B2 = (const float*)d_in[6];
    const float* HM = (const float*)d_in[7];
    const float* LQ = (const float*)d_in[8];
    const float* LR = (const float*)d_in[9];
    const float* LP0 = (const float*)d_in[10];
    float* out = (float*)d_out;
    ukf_kernel<<<dim3(B_LEN), dim3(128), 0, stream>>>(X0, U, Y, W1, B1, W2, B2,
                                                      HM, LQ, LR, LP0, out);
}